// Round 7
// baseline (376.196 us; speedup 1.0000x reference)
//
#include <hip/hip_runtime.h>
#include <hip/hip_bf16.h>
#include <math.h>

#define NB 4
#define NN 2048
#define DIMF 128
#define MD 16
#define KK 12
#define NODES (NB*NN)

typedef __attribute__((ext_vector_type(8))) short bf16x8;
typedef __attribute__((ext_vector_type(4))) float f32x4;

// silu via v_rcp (precise div is ~12 ops; rcp is 1ulp, irrelevant vs bf16 downstream)
__device__ __forceinline__ float silu_f(float x) {
    return x * __builtin_amdgcn_rcpf(1.0f + __expf(-x));
}

// fp32 -> bf16 (RNE)
__device__ __forceinline__ short f2bf(float x) {
    unsigned u = __float_as_uint(x);
    unsigned r = (u + 0x7FFFu + ((u >> 16) & 1u)) >> 16;
    return (short)r;
}

// packed fp32x2 -> bf16x2 (v_cvt_pk_bf16_f32 on gfx950)
__device__ __forceinline__ short2 pkbf(float a, float b) {
    union { __hip_bfloat162 h; short2 s; } u;
    u.h = __float22bfloat162_rn(make_float2(a, b));
    return u.s;
}

// unpack 8 bf16 (as uint4) -> 8 fp32
__device__ __forceinline__ void upk8(uint4 u, float* f) {
    f[0] = __uint_as_float(u.x << 16); f[1] = __uint_as_float(u.x & 0xFFFF0000u);
    f[2] = __uint_as_float(u.y << 16); f[3] = __uint_as_float(u.y & 0xFFFF0000u);
    f[4] = __uint_as_float(u.z << 16); f[5] = __uint_as_float(u.z & 0xFFFF0000u);
    f[6] = __uint_as_float(u.w << 16); f[7] = __uint_as_float(u.w & 0xFFFF0000u);
}

// ================= knn (512 thr, 8 queries/block): min pass1 + U-bound ===========
// 1024 blocks = 4 blocks/CU x 256 CU -> single round, 32 waves/CU.
// LDS floats: [0..6143] coords SoA; [6144+wv*32] lt_d2; [6400+wv*32] lt_ix;
// [6656+wv*12] eq_ix; [6752+wv*2] counters. (27,072 B of the 32,768 block.)
// Semantics identical to R6 (exact jax stable top-k; see R3-R6 derivations).
#define KNN_BIG 3.0e38f
#define KNN_CAP 32
#define FUS_SMEM 32768

__device__ __forceinline__ float dist2f(float dx, float dy, float dz) {
    return fmaf(dx, dx, fmaf(dy, dy, dz * dz));
}

__device__ __forceinline__ float wave_min_bcast64(float x) {
    int xi = __float_as_int(x);
    x = fminf(x, __int_as_float(__builtin_amdgcn_update_dpp(xi, xi, 0xB1, 0xf, 0xf, true)));
    xi = __float_as_int(x);
    x = fminf(x, __int_as_float(__builtin_amdgcn_update_dpp(xi, xi, 0x4E, 0xf, 0xf, true)));
    xi = __float_as_int(x);
    x = fminf(x, __int_as_float(__builtin_amdgcn_update_dpp(xi, xi, 0x141, 0xf, 0xf, true)));
    xi = __float_as_int(x);
    x = fminf(x, __int_as_float(__builtin_amdgcn_update_dpp(xi, xi, 0x140, 0xf, 0xf, true)));
    xi = __float_as_int(x);
    x = fminf(x, __int_as_float(__builtin_amdgcn_update_dpp(xi, xi, 0x142, 0xa, 0xf, true)));
    xi = __float_as_int(x);
    x = fminf(x, __int_as_float(__builtin_amdgcn_update_dpp(xi, xi, 0x143, 0xc, 0xf, true)));
    return __int_as_float(__builtin_amdgcn_readlane(__float_as_int(x), 63));
}

__device__ __forceinline__ int lane_rank(unsigned long long m) {
    return __builtin_amdgcn_mbcnt_hi((unsigned)(m >> 32),
           __builtin_amdgcn_mbcnt_lo((unsigned)m, 0));
}

__device__ __forceinline__ void knn_body(const float* __restrict__ coords,
                                         int* __restrict__ nbhd,
                                         int b2, int tid, float* sc) {
    int batch = b2 >> 8;                          // 256 blocks per batch
    int qbase = (b2 & 255) << 3;                  // 8 queries per block
    const float* cb = coords + (size_t)batch * NN * 3;
    int wv = tid >> 6, lane = tid & 63;
    int ql = qbase + wv;
    float qx = cb[3 * ql], qy = cb[3 * ql + 1], qz = cb[3 * ql + 2];
    // stage all 2048 points SoA: thread t -> points 4t..4t+3 (512 thr x 3 float4)
    {
        const float4* src = (const float4*)cb;
        float4 a = src[3 * tid], b4 = src[3 * tid + 1], c4 = src[3 * tid + 2];
        int o = tid * 4;
        float4 xs = {a.x, a.w, b4.z, c4.y};
        float4 ys = {a.y, b4.x, b4.w, c4.z};
        float4 zs = {a.z, b4.y, c4.x, c4.w};
        *(float4*)&sc[o]        = xs;
        *(float4*)&sc[2048 + o] = ys;
        *(float4*)&sc[4096 + o] = zs;
    }
    __syncthreads();

    // ---- pass 1: per-lane minimum only ----
    float mn = KNN_BIG;
#pragma unroll
    for (int g = 0; g < 8; ++g) {
        int base = g * 256 + lane * 4;
        float4 xs = *(const float4*)&sc[base];
        float4 ys = *(const float4*)&sc[2048 + base];
        float4 zs = *(const float4*)&sc[4096 + base];
        mn = fminf(mn, dist2f(xs.x - qx, ys.x - qy, zs.x - qz));
        mn = fminf(mn, dist2f(xs.y - qx, ys.y - qy, zs.y - qz));
        mn = fminf(mn, dist2f(xs.z - qx, ys.z - qy, zs.z - qz));
        mn = fminf(mn, dist2f(xs.w - qx, ys.w - qy, zs.w - qz));
    }

    // ---- U = 12th smallest of per-lane minima (>= exact T) ----
    float U = KNN_BIG;
    {
        float v = mn;
        int got = 0;
#pragma unroll 1
        for (int pass = 0; pass < 12; ++pass) {
            float mv = wave_min_bcast64(v);
            U = mv;
            got += (int)__popcll(__ballot(v == mv));
            if (got >= 12) break;
            if (v == mv) v = KNN_BIG;
        }
    }

    // ---- pass 2: recompute from LDS; atomic-slot compaction (unordered) ----
    float* lt_d2 = sc + 6144 + wv * KNN_CAP;
    int*   lt_ix = (int*)(sc + 6400) + wv * KNN_CAP;
    int*   eq_ix = (int*)(sc + 6656) + wv * 12;
    int*   cntp  = (int*)(sc + 6752) + wv * 2;
    if (lane == 0) { cntp[0] = 0; cntp[1] = 0; }
#pragma unroll 2
    for (int g = 0; g < 8; ++g) {
        int base = g * 256 + lane * 4;
        float4 xs = *(const float4*)&sc[base];
        float4 ys = *(const float4*)&sc[2048 + base];
        float4 zs = *(const float4*)&sc[4096 + base];
        float dd[4];
        dd[0] = dist2f(xs.x - qx, ys.x - qy, zs.x - qz);
        dd[1] = dist2f(xs.y - qx, ys.y - qy, zs.y - qz);
        dd[2] = dist2f(xs.z - qx, ys.z - qy, zs.z - qz);
        dd[3] = dist2f(xs.w - qx, ys.w - qy, zs.w - qz);
#pragma unroll
        for (int u = 0; u < 4; ++u) {
            float d2 = dd[u];
            if (d2 < U) {
                int s = atomicAdd(cntp, 1);
                if (s < KNN_CAP) { lt_d2[s] = d2; lt_ix[s] = base + u; }
            } else if (d2 == U) {
                int s = atomicAdd(cntp + 1, 1);
                if (s < 12) eq_ix[s] = base + u;
            }
        }
    }
    int cnt_lt = cntp[0], cnt_eq = cntp[1];

    float T = U;
    if (__builtin_expect(cnt_lt > KNN_CAP, 0)) {
        // exact fallback: per-lane top-12 from LDS -> exact T -> ballot recollect
        float kd12[12];
#pragma unroll
        for (int r = 0; r < 12; ++r) kd12[r] = KNN_BIG;
        for (int g = 0; g < 8; ++g) {
            int base = g * 256 + lane * 4;
            float4 xs = *(const float4*)&sc[base];
            float4 ys = *(const float4*)&sc[2048 + base];
            float4 zs = *(const float4*)&sc[4096 + base];
            float dd[4];
            dd[0] = dist2f(xs.x - qx, ys.x - qy, zs.x - qz);
            dd[1] = dist2f(xs.y - qx, ys.y - qy, zs.y - qz);
            dd[2] = dist2f(xs.z - qx, ys.z - qy, zs.z - qz);
            dd[3] = dist2f(xs.w - qx, ys.w - qy, zs.w - qz);
#pragma unroll
            for (int u = 0; u < 4; ++u) {
                float cv = dd[u];
#pragma unroll
                for (int r = 0; r < 12; ++r) {
                    float lo = fminf(kd12[r], cv);
                    cv = fmaxf(kd12[r], cv);
                    kd12[r] = lo;
                }
            }
        }
        int got = 0;
#pragma unroll 1
        for (int pass = 0; pass < 12; ++pass) {
            float mv = wave_min_bcast64(kd12[0]);
            T = mv;
            got += (int)__popcll(__ballot(kd12[0] == mv));
            if (got >= 12) break;
            if (kd12[0] == mv) {
#pragma unroll
                for (int r = 0; r < 11; ++r) kd12[r] = kd12[r + 1];
                kd12[11] = KNN_BIG;
            }
        }
        cnt_lt = 0; cnt_eq = 0;
        for (int g = 0; g < 8; ++g) {
            int base = g * 256 + lane * 4;
            float4 xs = *(const float4*)&sc[base];
            float4 ys = *(const float4*)&sc[2048 + base];
            float4 zs = *(const float4*)&sc[4096 + base];
            float dd[4];
            dd[0] = dist2f(xs.x - qx, ys.x - qy, zs.x - qz);
            dd[1] = dist2f(xs.y - qx, ys.y - qy, zs.y - qz);
            dd[2] = dist2f(xs.z - qx, ys.z - qy, zs.z - qz);
            dd[3] = dist2f(xs.w - qx, ys.w - qy, zs.w - qz);
#pragma unroll
            for (int u = 0; u < 4; ++u) {
                float d2 = dd[u];
                bool lt = d2 < T;
                unsigned long long bl = __ballot(lt);
                if (lt) {
                    int s = cnt_lt + lane_rank(bl);
                    if (s < KNN_CAP) { lt_d2[s] = d2; lt_ix[s] = base + u; }
                }
                cnt_lt += (int)__popcll(bl);
                bool eq = (d2 == T);
                unsigned long long be = __ballot(eq);
                if (eq) {
                    int s = cnt_eq + lane_rank(be);
                    if (s < 12) eq_ix[s] = base + u;
                }
                cnt_eq += (int)__popcll(be);
            }
        }
    }

    // ---- rank survivors by (d2, idx): exact reference stable top-k ----
    int C_lt = cnt_lt < KNN_CAP ? cnt_lt : KNN_CAP;
    int C_eq = cnt_eq < 12 ? cnt_eq : 12;
    int C = C_lt + C_eq;
    float md2 = KNN_BIG; int mix = 0x7FFFFFFF;
    if (lane < C_lt)      { md2 = lt_d2[lane]; mix = lt_ix[lane]; }
    else if (lane < C)    { md2 = T;           mix = eq_ix[lane - C_lt]; }
    int rank = 0;
#pragma unroll 1
    for (int j = 0; j < C; ++j) {
        float dj = __shfl(md2, j);
        int   ij = __shfl(mix, j);
        if (dj < md2 || (dj == md2 && ij < mix)) ++rank;
    }
    if (lane < C && rank < 12)
        nbhd[((size_t)batch * NN + ql) * KK + rank] = batch * NN + mix;
}

// ================= fused knn(0) + embed + prep (512 thr) =========================
// blocks 0..1023 knn; 1024..3071 embed (512 elems each); 3072..4819 prep.
__global__ __launch_bounds__(512, 8) void embed_knn_kernel(
    const float* __restrict__ feats, const float* __restrict__ w,
    const float* __restrict__ b, float* __restrict__ h,
    unsigned short* __restrict__ hbf,
    const float* __restrict__ coords, int* __restrict__ nbhd,
    const float* __restrict__ ew2, const float* __restrict__ cw1,
    const float* __restrict__ ew1, const float* __restrict__ nw1,
    const float* __restrict__ nw2,
    unsigned short* __restrict__ ew2frag, unsigned short* __restrict__ cw1frag,
    unsigned short* __restrict__ Btf, unsigned short* __restrict__ Bt1f,
    unsigned short* __restrict__ Bt2f)
{
    __shared__ __attribute__((aligned(16))) char smem[FUS_SMEM];
    int tid = threadIdx.x;
    int bid = (int)blockIdx.x;
    if (bid < 1024) {
        knn_body(coords, nbhd, bid, tid, (float*)smem);
    } else if (bid < 3072) {
        int idx = (bid - 1024) * 512 + tid;
        int n = idx >> 7, d = idx & 127;
        const float* fr = feats + n * 10;
        float acc = b[d];
#pragma unroll
        for (int f = 0; f < 10; ++f) acc = fmaf(fr[f], w[f * 128 + d], acc);
        h[idx] = acc;
        hbf[idx] = (unsigned short)f2bf(acc);
    } else {
        int t = (bid - 3072) * 512 + tid;
        if (t < 43008) {                              // 4 layers x (8704 + 2048)
            int l = t / 10752, r = t % 10752;
            if (r < 8704) {
                int kc = r >> 9, lane = (r >> 3) & 63, j = r & 7;
                int k = kc * 32 + ((lane >> 4) << 3) + j, n = lane & 15;
                float v = (k < 514) ? ew2[(size_t)l * 514 * 16 + k * 16 + n] : 0.0f;
                ew2frag[(size_t)l * 8704 + r] = (unsigned short)f2bf(v);
            } else {
                int r2 = r - 8704;
                int nb = r2 >> 9, lane = (r2 >> 3) & 63, j = r2 & 7;
                int c = ((lane >> 4) << 3) + j, n = nb * 16 + (lane & 15);
                float v = (c < 16) ? cw1[(size_t)l * 1024 + c * 64 + n] : 0.0f;
                cw1frag[(size_t)l * 2048 + r2] = (unsigned short)f2bf(v);
            }
        } else if (t < 600064) {
            // Btf[l][c][k]: c<514 -> ew1[l][k][c]; 514..1027 -> ew1[l][128+k][c-514]
            int t2 = t - 43008;
            int l = t2 / 139264, r2 = t2 % 139264;
            int k = r2 / 1088, c = r2 - k * 1088;
            const float* e1 = ew1 + (size_t)l * 257 * 514;
            float v = 0.0f;
            if (c < 514)       v = e1[k * 514 + c];
            else if (c < 1028) v = e1[(128 + k) * 514 + (c - 514)];
            Btf[(size_t)l * 139264 + c * 128 + k] = (unsigned short)f2bf(v);
        } else if (t < 763904) {
            // Bt1f[l][c(256)][k(160)] from nw1[l][144][256], k>=144 zero
            int t2 = t - 600064;
            int l = t2 / 40960, r2 = t2 % 40960;
            int c = r2 / 160, k = r2 - c * 160;
            float v = (k < 144) ? nw1[(size_t)l * 144 * 256 + k * 256 + c] : 0.0f;
            Bt1f[(size_t)l * 40960 + c * 160 + k] = (unsigned short)f2bf(v);
        } else if (t < 894976) {
            // Bt2f[l][c(128)][k(256)] from nw2[l][256][128]
            int t2 = t - 763904;
            int l = t2 / 32768, r2 = t2 % 32768;
            int c = r2 / 256, k = r2 - c * 256;
            float v = nw2[(size_t)l * 256 * 128 + k * 128 + c];
            Bt2f[(size_t)l * 32768 + c * 256 + k] = (unsigned short)f2bf(v);
        }
    }
}

// ================= fused knn(l+1) + node-MLP (512 thr) ===========================
// blocks 0..knnb-1: knn (long poles first); knnb..knnb+127: gemm, 64 rows each.
// Gemm: 8 waves = rg(4 row-groups of 16) x ch(2 col-halves of 64); t1[64][256]
// via 2 column-halves in LDS (t1h), K split 160=5 ksteps then 2x4 ksteps.
__global__ __launch_bounds__(512, 8) void node_knn_kernel(
    const unsigned short* __restrict__ hbf,   // [8192][128]
    const unsigned short* __restrict__ mbuf,  // [8192][16]
    const unsigned short* __restrict__ Bt1l,  // [256][160]
    const unsigned short* __restrict__ Bt2l,  // [128][256]
    const float* __restrict__ nb1l,           // 256
    const float* __restrict__ nb2l,           // 128
    const float* __restrict__ hin,            // resid [8192][128] fp32
    float* __restrict__ hout,
    unsigned short* __restrict__ hbfout,
    const float* __restrict__ coordsN, int* __restrict__ nbhd, int knnb)
{
    __shared__ __attribute__((aligned(16))) char smem[FUS_SMEM];
    int tid = threadIdx.x;
    int bid = (int)blockIdx.x;
    if (bid < knnb) {
        knn_body(coordsN, nbhd, bid, tid, (float*)smem);
        return;
    }
    int gb = bid - knnb;                          // 0..127
    unsigned short (*sA)[40]   = (unsigned short(*)[40])smem;             // [64][40]
    unsigned short (*sB)[40]   = (unsigned short(*)[40])(smem + 5120);    // [128][40]
    unsigned short (*t1h)[136] = (unsigned short(*)[136])(smem + 15360);  // [64][136]
    int lane = tid & 63, w = tid >> 6, quad = lane >> 4, l16 = lane & 15;
    int rg = w >> 1, ch = w & 1;
    int rowBase = gb * 64;
    int bcol = tid >> 2, bs8 = (tid & 3) * 8;     // B staging: 128 cols x 4 k-slots
    int ar = tid >> 2, ak8 = (tid & 3) * 8;       // A staging (tid<256): 64 rows

    f32x4 acc2[4];
#pragma unroll
    for (int ct = 0; ct < 4; ++ct) acc2[ct] = (f32x4){0.f, 0.f, 0.f, 0.f};

#pragma unroll 1
    for (int hf = 0; hf < 2; ++hf) {
        // ---- phase 1: t1[:, hf*128 .. +128] = silu(A(144) x Bt1 + nb1) ----
        f32x4 acc1[4];
#pragma unroll
        for (int ct = 0; ct < 4; ++ct) acc1[ct] = (f32x4){0.f, 0.f, 0.f, 0.f};
#pragma unroll 1
        for (int kc = 0; kc < 5; ++kc) {
            int k0 = kc * 32;
            if (tid < 256) {
                int kg = k0 + ak8;
                uint4 v = {0u, 0u, 0u, 0u};
                if (kg < 128)
                    v = *(const uint4*)&hbf[(size_t)(rowBase + ar) * 128 + kg];
                else if (kg < 144)
                    v = *(const uint4*)&mbuf[(size_t)(rowBase + ar) * 16 + (kg - 128)];
                *(uint4*)&sA[ar][ak8] = v;
            }
            *(uint4*)&sB[bcol][bs8] =
                *(const uint4*)(Bt1l + (size_t)(hf * 128 + bcol) * 160 + k0 + bs8);
            __syncthreads();
            bf16x8 a = *(const bf16x8*)&sA[rg * 16 + l16][quad * 8];
            bf16x8 bfr[4];
#pragma unroll
            for (int ct = 0; ct < 4; ++ct)
                bfr[ct] = *(const bf16x8*)&sB[ch * 64 + ct * 16 + l16][quad * 8];
#pragma unroll
            for (int ct = 0; ct < 4; ++ct)
                acc1[ct] = __builtin_amdgcn_mfma_f32_16x16x32_bf16(a, bfr[ct], acc1[ct], 0, 0, 0);
            __syncthreads();
        }
        // t1 epilogue -> LDS
#pragma unroll
        for (int ct = 0; ct < 4; ++ct) {
            int col = ch * 64 + ct * 16 + l16;
            float bv = nb1l[hf * 128 + col];
#pragma unroll
            for (int r = 0; r < 4; ++r)
                t1h[rg * 16 + quad * 4 + r][col] =
                    (unsigned short)f2bf(silu_f(acc1[ct][r] + bv));
        }
        __syncthreads();
        // ---- phase 2 partial: acc2 += t1h x Bt2[k = hf*128 ..] ----
#pragma unroll 1
        for (int kc2 = 0; kc2 < 4; ++kc2) {
            *(uint4*)&sB[bcol][bs8] =
                *(const uint4*)(Bt2l + (size_t)bcol * 256 + hf * 128 + kc2 * 32 + bs8);
            __syncthreads();
            bf16x8 a = *(const bf16x8*)&t1h[rg * 16 + l16][kc2 * 32 + quad * 8];
            bf16x8 bfr[4];
#pragma unroll
            for (int ct = 0; ct < 4; ++ct)
                bfr[ct] = *(const bf16x8*)&sB[ch * 64 + ct * 16 + l16][quad * 8];
#pragma unroll
            for (int ct = 0; ct < 4; ++ct)
                acc2[ct] = __builtin_amdgcn_mfma_f32_16x16x32_bf16(a, bfr[ct], acc2[ct], 0, 0, 0);
            __syncthreads();
        }
    }
    // ---- epilogue: h' = acc2 + nb2 + hin (residual); fp32 + bf16 out ----
#pragma unroll
    for (int ct = 0; ct < 4; ++ct) {
        int col = ch * 64 + ct * 16 + l16;
        float bv = nb2l[col];
#pragma unroll
        for (int r = 0; r < 4; ++r) {
            int row = rowBase + rg * 16 + quad * 4 + r;
            float v = acc2[ct][r] + bv + hin[(size_t)row * 128 + col];
            hout[(size_t)row * 128 + col] = v;
            hbfout[(size_t)row * 128 + col] = (unsigned short)f2bf(v);
        }
    }
}

// ================= merged P/Q GEMM: A (bf16 hbf) + B (bf16 Btf), uint4 staging ====
__global__ __launch_bounds__(256) void pq_gemm_kernel(
    const unsigned short* __restrict__ Abf,    // hbf [8192][128]
    const unsigned short* __restrict__ Bt,     // [1088 cols][128 k] bf16, layer slice
    unsigned short* __restrict__ PQb,
    const float* __restrict__ bias)
{
    __shared__ __attribute__((aligned(16))) unsigned short sA[128][40];
    __shared__ __attribute__((aligned(16))) unsigned short sBt[64][40];
    int tid = threadIdx.x;
    int lane = tid & 63, w = tid >> 6, quad = lane >> 4, l16 = lane & 15;
    int rowBase = blockIdx.y * 128;
    int colBase = blockIdx.x * 64;
    f32x4 acc[2][4];
#pragma unroll
    for (int rt = 0; rt < 2; ++rt)
#pragma unroll
        for (int ct = 0; ct < 4; ++ct) acc[rt][ct] = (f32x4){0.f, 0.f, 0.f, 0.f};

    int bc = tid >> 2, bk8 = (tid & 3) * 8;
    const unsigned short* bsrc = Bt + (size_t)(colBase + bc) * 128 + bk8;

#pragma unroll
    for (int kc = 0; kc < 4; ++kc) {
        int k0 = kc * 32;
#pragma unroll
        for (int p = 0; p < 2; ++p) {
            int e = tid + p * 256;
            int r = e >> 2, k8 = (e & 3) * 8;
            *(uint4*)&sA[r][k8] = *(const uint4*)&Abf[(size_t)(rowBase + r) * 128 + k0 + k8];
        }
        *(uint4*)&sBt[bc][bk8] = *(const uint4*)(bsrc + k0);
        __syncthreads();
        bf16x8 a[2], b[4];
#pragma unroll
        for (int rt = 0; rt < 2; ++rt)
            a[rt] = *(const bf16x8*)&sA[w * 32 + rt * 16 + l16][quad * 8];
#pragma unroll
        for (int ct = 0; ct < 4; ++ct)
            b[ct] = *(const bf16x8*)&sBt[ct * 16 + l16][quad * 8];
#pragma unroll
        for (int rt = 0; rt < 2; ++rt)
#pragma unroll
            for (int ct = 0; ct < 4; ++ct)
                acc[rt][ct] = __builtin_amdgcn_mfma_f32_16x16x32_bf16(a[rt], b[ct], acc[rt][ct], 0, 0, 0);
        __syncthreads();
    }
#pragma unroll
    for (int rt = 0; rt < 2; ++rt) {
#pragma unroll
        for (int ct = 0; ct < 4; ++ct) {
            int col = colBase + ct * 16 + l16;
            if (col < 1028) {
                bool isP = col < 514;
                int oc = isP ? col : col + 14;
                float bv = isP ? bias[col] : 0.0f;
#pragma unroll
                for (int r = 0; r < 4; ++r) {
                    int row = rowBase + w * 32 + rt * 16 + quad * 4 + r;
                    PQb[(size_t)row * 1056 + oc] = (unsigned short)f2bf(acc[rt][ct][r] + bv);
                }
            }
        }
    }
}

// ================= edge kernel: 192 thr / 4 nodes; m-sums -> bf16 mbuf ===========
__global__ __launch_bounds__(192, 6) void edge_kernel(
    const unsigned short* __restrict__ PQ, const int* __restrict__ nbhd,
    const float* __restrict__ cin, float* __restrict__ cout,
    unsigned short* __restrict__ mbuf,
    const float* __restrict__ wrow,            // raw ew1[l][256][0:514]
    const unsigned short* __restrict__ ew2f,   // [17][64][8] bf16 frags (global)
    const unsigned short* __restrict__ cw1f,   // [4][64][8] bf16 frags (global)
    const float* __restrict__ eb2l,            // 16
    const float* __restrict__ cb1l,            // 64
    const float* __restrict__ cw2l,            // 64
    const float* __restrict__ cb2l,            // 1
    const float* __restrict__ cscalel)         // 1
{
    __shared__ __attribute__((aligned(16))) float swl[544];
    __shared__ __attribute__((aligned(16))) unsigned short mbf[48][16];
    __shared__ __attribute__((aligned(16))) float mf32[48][16];
    __shared__ __attribute__((aligned(16))) float reld2[48][4];
    __shared__ float wall[48];
    int tid = threadIdx.x;

    for (int idx = tid; idx < 544; idx += 192)
        swl[idx] = (idx < 514) ? wrow[idx] : 0.0f;
    __syncthreads();

    int lane = tid & 63, w = tid >> 6;               // w in 0..2
    int quad = lane >> 4, e16 = lane & 15;
    int eloc = w * 16 + e16;                         // 0..47
    int nloc = eloc / 12;                            // 0..3
    int k12 = eloc - nloc * 12;
    // XCD swizzle: bid -> (batch, within-batch group); bijective over 2048.
    int bid = blockIdx.x;
    int rr8 = bid & 7, bsw = rr8 >> 1;
    int wsw = ((bid >> 3) << 1) | (rr8 & 1);
    int nodeBase = bsw * 2048 + wsw * 4;
    int i = nodeBase + nloc;
    int j = nbhd[i * KK + k12];
    float cix = cin[i * 3], ciy = cin[i * 3 + 1], ciz = cin[i * 3 + 2];
    float rx = cix - cin[j * 3], ry = ciy - cin[j * 3 + 1], rz = ciz - cin[j * 3 + 2];
    float d2 = rx * rx + ry * ry + rz * rz;

    const unsigned short* Pp = PQ + (size_t)i * 1056 + quad * 8;
    const unsigned short* Qp = PQ + (size_t)j * 1056 + 528 + quad * 8;

    uint4 pb[3], qb[3];
    pb[0] = *(const uint4*)Pp;
    qb[0] = *(const uint4*)Qp;
    pb[1] = *(const uint4*)(Pp + 32);
    qb[1] = *(const uint4*)(Qp + 32);

    f32x4 acc = {0.0f, 0.0f, 0.0f, 0.0f};
#pragma unroll
    for (int kc = 0; kc < 16; ++kc) {
        int cur = kc % 3, nx = (kc + 2) % 3;
        if (kc < 14) {
            pb[nx] = *(const uint4*)(Pp + (kc + 2) * 32);
            qb[nx] = *(const uint4*)(Qp + (kc + 2) * 32);
        }
        float p[8], q[8];
        upk8(pb[cur], p); upk8(qb[cur], q);
        float4 w0 = *(const float4*)&swl[quad * 8 + kc * 32];
        float4 w1 = *(const float4*)&swl[quad * 8 + kc * 32 + 4];
        float h0 = silu_f(fmaf(d2, w0.x, p[0] + q[0]));
        float h1 = silu_f(fmaf(d2, w0.y, p[1] + q[1]));
        float h2 = silu_f(fmaf(d2, w0.z, p[2] + q[2]));
        float h3 = silu_f(fmaf(d2, w0.w, p[3] + q[3]));
        float h4 = silu_f(fmaf(d2, w1.x, p[4] + q[4]));
        float h5 = silu_f(fmaf(d2, w1.y, p[5] + q[5]));
        float h6 = silu_f(fmaf(d2, w1.z, p[6] + q[6]));
        float h7 = silu_f(fmaf(d2, w1.w, p[7] + q[7]));
        bf16x8 af;
        short2 r0 = pkbf(h0, h1), r1 = pkbf(h2, h3), r2 = pkbf(h4, h5), r3 = pkbf(h6, h7);
        af[0] = r0.x; af[1] = r0.y; af[2] = r1.x; af[3] = r1.y;
        af[4] = r2.x; af[5] = r2.y; af[6] = r3.x; af[7] = r3.y;
        bf16x8 bf = *(const bf16x8*)(ew2f + (((size_t)kc * 64 + lane) << 3));
        acc = __builtin_amdgcn_mfma_f32_16x16x32_bf16(af, bf, acc, 0, 0, 0);
    }
    {   // tail: k=512,513
        unsigned up = *(const unsigned*)(PQ + (size_t)i * 1056 + 512);
        unsigned uq = *(const unsigned*)(PQ + (size_t)j * 1056 + 528 + 512);
        bf16x8 af = {0, 0, 0, 0, 0, 0, 0, 0};
        if (quad == 0) {
            float px = __uint_as_float(up << 16), py = __uint_as_float(up & 0xFFFF0000u);
            float qx = __uint_as_float(uq << 16), qy = __uint_as_float(uq & 0xFFFF0000u);
            af[0] = f2bf(silu_f(fmaf(d2, swl[512], px + qx)));
            af[1] = f2bf(silu_f(fmaf(d2, swl[513], py + qy)));
        }
        bf16x8 bf = *(const bf16x8*)(ew2f + (((size_t)16 * 64 + lane) << 3));
        acc = __builtin_amdgcn_mfma_f32_16x16x32_bf16(af, bf, acc, 0, 0, 0);
    }

    float eb = eb2l[e16];
    float m[4];
#pragma unroll
    for (int r = 0; r < 4; ++r) m[r] = silu_f(acc[r] + eb);

#pragma unroll
    for (int r = 0; r < 4; ++r) {
        int row = w * 16 + quad * 4 + r;
        mbf[row][e16] = (unsigned short)f2bf(m[r]);
        mf32[row][e16] = m[r];
    }
    if (quad == 0) {
        reld2[eloc][0] = rx; reld2[eloc][1] = ry;
        reld2[eloc][2] = rz; reld2[eloc][3] = d2;
    }
    __syncthreads();

    if (tid < 64) {
        int n = tid >> 4, ch = tid & 15;
        float s = 0.0f;
#pragma unroll
        for (int ke = 0; ke < KK; ++ke) s += mf32[n * 12 + ke][ch];
        mbuf[(size_t)(nodeBase + n) * 16 + ch] = (unsigned short)f2bf(s);
    }

    bf16x8 af2 = {0, 0, 0, 0, 0, 0, 0, 0};
    if (quad < 2) af2 = *(const bf16x8*)&mbf[w * 16 + e16][quad * 8];
    float wpart[4] = {0.0f, 0.0f, 0.0f, 0.0f};
#pragma unroll
    for (int nb = 0; nb < 4; ++nb) {
        bf16x8 cf = *(const bf16x8*)(cw1f + (((size_t)nb * 64 + lane) << 3));
        f32x4 z = {0.0f, 0.0f, 0.0f, 0.0f};
        f32x4 t = __builtin_amdgcn_mfma_f32_16x16x32_bf16(af2, cf, z, 0, 0, 0);
        int d = nb * 16 + e16;
        float cb = cb1l[d], cw = cw2l[d];
#pragma unroll
        for (int r = 0; r < 4; ++r)
            wpart[r] = fmaf(silu_f(t[r] + cb), cw, wpart[r]);
    }
#pragma unroll
    for (int o = 1; o < 16; o <<= 1)
#pragma unroll
        for (int r = 0; r < 4; ++r) wpart[r] += __shfl_xor(wpart[r], o);
    if (e16 == 0) {
        float cb2v = cb2l[0];
#pragma unroll
        for (int r = 0; r < 4; ++r) {
            float ww = wpart[r] + cb2v;
            ww = fminf(fmaxf(ww, -2.0f), 2.0f);
            wall[w * 16 + quad * 4 + r] = ww;
        }
    }
    __syncthreads();

    if (tid < 12) {
        int n = tid / 3, c = tid - n * 3;
        float cs = cscalel[0];
        float s = 0.0f;
#pragma unroll
        for (int ke = 0; ke < KK; ++ke) {
            int eo = n * 12 + ke;
            float d2e = reld2[eo][3];
            float f = wall[eo] * cs * __builtin_amdgcn_rcpf(fmaxf(sqrtf(d2e), 1e-8f));
            s = fmaf(f, reld2[eo][c], s);
        }
        int node = nodeBase + n;
        cout[node * 3 + c] = cin[node * 3 + c] + s;
    }
}

// ---------------- final: two-stage mean reduction ----------------
__global__ __launch_bounds__(256) void final1_kernel(const float* __restrict__ h,
                                                     float* __restrict__ part) {
    int b = blockIdx.x >> 5, sl = blockIdx.x & 31;
    int d = threadIdx.x & 127, half = threadIdx.x >> 7;
    const float* hp = h + ((size_t)b * NN + sl * 64) * DIMF;
    float acc = 0.0f;
    for (int n = half; n < 64; n += 2) acc += hp[(size_t)n * DIMF + d];
    __shared__ float red[256];
    red[threadIdx.x] = acc;
    __syncthreads();
    if (half == 0) part[(size_t)blockIdx.x * DIMF + d] = red[d] + red[d + 128];
}

__global__ __launch_bounds__(128) void final2_kernel(const float* __restrict__ part,
                                                     float* __restrict__ out) {
    int b = blockIdx.x, d = threadIdx.x;
    float acc = 0.0f;
#pragma unroll
    for (int s = 0; s < 32; ++s) acc += part[(size_t)(b * 32 + s) * DIMF + d];
    out[b * DIMF + d] = acc * (1.0f / NN);
}

extern "C" void kernel_launch(void* const* d_in, const int* in_sizes, int n_in,
                              void* d_out, int out_size, void* d_ws, size_t ws_size,
                              hipStream_t stream) {
    const float* feats  = (const float*)d_in[0];
    const float* coords = (const float*)d_in[1];
    // d_in[2] = mask (all true) -- unused
    const float* emb_w  = (const float*)d_in[3];
    const float* emb_b  = (const float*)d_in[4];
    const float* ew1    = (const float*)d_in[5];
    const float* eb1    = (const float*)d_in[6];
    const float* ew2    = (const float*)d_in[7];
    const float* eb2    = (const float*)d_in[8];
    const float* cw1    = (const float*)d_in[9];
    const float* cb1    = (const float*)d_in[10];
    const float* cw2    = (const float*)d_in[11];
    const float* cb2    = (const float*)d_in[12];
    const float* cscale = (const float*)d_in[13];
    const float* nw1    = (const float*)d_in[14];
    const float* nb1    = (const float*)d_in[15];
    const float* nw2    = (const float*)d_in[16];
    const float* nb2    = (const float*)d_in[17];

    // workspace: within proven 47,513,600 B footprint
    char* ws = (char*)d_ws;
    float* h0     = (float*)(ws + 0);
    float* h1     = (float*)(ws + 4194304);
    float* c0     = (float*)(ws + 8388608);
    float* c1     = (float*)(ws + 8486912);
    int*   nbhd   = (int*)  (ws + 8585216);
    unsigned short* hbf0 = (unsigned short*)(ws + 8978432);     // 2,097,152 B
    unsigned short* hbf1 = (unsigned short*)(ws + 11075584);    // -> 13,172,736
    unsigned short* PQb = (unsigned short*)(ws + 13697024);     // 8192x1056 bf16
    unsigned short* ew2frag = (unsigned short*)(ws + 35651584); // 69,632 B
    unsigned short* cw1frag = (unsigned short*)(ws + 35721216); // 16,384 B
    unsigned short* Btf     = (unsigned short*)(ws + 35737600); // 1,114,112 -> 36,851,712
    unsigned short* mbuf    = (unsigned short*)(ws + 36851712); // 262,144 -> 37,113,856
    unsigned short* Bt1f    = (unsigned short*)(ws + 37113856); // 327,680 -> 37,441,536
    unsigned short* Bt2f    = (unsigned short*)(ws + 37441536); // 262,144 -> 37,703,680
    float* part   = (float*)(ws + 13697024);                    // alias, after layers

    float* hbuf[2] = {h0, h1};
    float* cbuf[2] = {c0, c1};
    unsigned short* hbfb[2] = {hbf0, hbf1};

    // fused knn(0) + embed + prep: 0..1023 knn, 1024..3071 embed, 3072..4819 prep
    embed_knn_kernel<<<4820, 512, 0, stream>>>(feats, emb_w, emb_b, h0, hbf0,
        coords, nbhd, ew2, cw1, ew1, nw1, nw2, ew2frag, cw1frag, Btf, Bt1f, Bt2f);

    for (int l = 0; l < 4; ++l) {
        const float* hin  = hbuf[l & 1];
        float*       hout = hbuf[(l + 1) & 1];
        unsigned short* hbfin  = hbfb[l & 1];
        unsigned short* hbfout = hbfb[(l + 1) & 1];
        const float* cin  = (l == 0) ? coords : cbuf[(l - 1) & 1];
        float*       cout = cbuf[l & 1];
        const float* ew1l = ew1 + (size_t)l * 257 * 514;

        pq_gemm_kernel<<<dim3(17, 64), 256, 0, stream>>>(
            hbfin, Btf + (size_t)l * 139264, PQb, eb1 + l * 514);

        edge_kernel<<<NODES / 4, 192, 0, stream>>>(PQb, nbhd, cin, cout, mbuf,
            ew1l + 256 * 514, ew2frag + (size_t)l * 8704, cw1frag + (size_t)l * 2048,
            eb2 + l * 16, cb1 + l * 64, cw2 + l * 64, cb2 + l, cscale + l);

        // fused knn(l+1) (1024 blocks first) + node-MLP (128 gemm blocks)
        int knnb = (l < 3) ? 1024 : 0;
        node_knn_kernel<<<knnb + 128, 512, 0, stream>>>(
            hbfin, mbuf, Bt1f + (size_t)l * 40960, Bt2f + (size_t)l * 32768,
            nb1 + l * 256, nb2 + l * 128, hin, hout, hbfout,
            cout, nbhd, knnb);
    }

    final1_kernel<<<NB * 32, 256, 0, stream>>>(hbuf[0], part);
    final2_kernel<<<NB, 128, 0, stream>>>(part, (float*)d_out);
}

// Round 8
// 352.841 us; speedup vs baseline: 1.0662x; 1.0662x over previous
//
#include <hip/hip_runtime.h>
#include <hip/hip_bf16.h>
#include <math.h>

#define NB 4
#define NN 2048
#define DIMF 128
#define MD 16
#define KK 12
#define NODES (NB*NN)

typedef __attribute__((ext_vector_type(8))) short bf16x8;
typedef __attribute__((ext_vector_type(4))) float f32x4;

// silu via v_rcp (precise div is ~12 ops; rcp is 1ulp, irrelevant vs bf16 downstream)
__device__ __forceinline__ float silu_f(float x) {
    return x * __builtin_amdgcn_rcpf(1.0f + __expf(-x));
}

// fp32 -> bf16 (RNE)
__device__ __forceinline__ short f2bf(float x) {
    unsigned u = __float_as_uint(x);
    unsigned r = (u + 0x7FFFu + ((u >> 16) & 1u)) >> 16;
    return (short)r;
}

// packed fp32x2 -> bf16x2 (v_cvt_pk_bf16_f32 on gfx950)
__device__ __forceinline__ short2 pkbf(float a, float b) {
    union { __hip_bfloat162 h; short2 s; } u;
    u.h = __float22bfloat162_rn(make_float2(a, b));
    return u.s;
}

// unpack 8 bf16 (as uint4) -> 8 fp32
__device__ __forceinline__ void upk8(uint4 u, float* f) {
    f[0] = __uint_as_float(u.x << 16); f[1] = __uint_as_float(u.x & 0xFFFF0000u);
    f[2] = __uint_as_float(u.y << 16); f[3] = __uint_as_float(u.y & 0xFFFF0000u);
    f[4] = __uint_as_float(u.z << 16); f[5] = __uint_as_float(u.z & 0xFFFF0000u);
    f[6] = __uint_as_float(u.w << 16); f[7] = __uint_as_float(u.w & 0xFFFF0000u);
}

// ================= knn: min-only pass 1 + U-bound + LDS-atomic compaction =========
// (R6-proven body; exact jax stable top-k. See R3-R6 derivations.)
#define KNN_BIG 3.0e38f
#define KNN_CAP 32
#define KNN_SMEM 25856

__device__ __forceinline__ float dist2f(float dx, float dy, float dz) {
    return fmaf(dx, dx, fmaf(dy, dy, dz * dz));
}

__device__ __forceinline__ float wave_min_bcast64(float x) {
    int xi = __float_as_int(x);
    x = fminf(x, __int_as_float(__builtin_amdgcn_update_dpp(xi, xi, 0xB1, 0xf, 0xf, true)));
    xi = __float_as_int(x);
    x = fminf(x, __int_as_float(__builtin_amdgcn_update_dpp(xi, xi, 0x4E, 0xf, 0xf, true)));
    xi = __float_as_int(x);
    x = fminf(x, __int_as_float(__builtin_amdgcn_update_dpp(xi, xi, 0x141, 0xf, 0xf, true)));
    xi = __float_as_int(x);
    x = fminf(x, __int_as_float(__builtin_amdgcn_update_dpp(xi, xi, 0x140, 0xf, 0xf, true)));
    xi = __float_as_int(x);
    x = fminf(x, __int_as_float(__builtin_amdgcn_update_dpp(xi, xi, 0x142, 0xa, 0xf, true)));
    xi = __float_as_int(x);
    x = fminf(x, __int_as_float(__builtin_amdgcn_update_dpp(xi, xi, 0x143, 0xc, 0xf, true)));
    return __int_as_float(__builtin_amdgcn_readlane(__float_as_int(x), 63));
}

__device__ __forceinline__ int lane_rank(unsigned long long m) {
    return __builtin_amdgcn_mbcnt_hi((unsigned)(m >> 32),
           __builtin_amdgcn_mbcnt_lo((unsigned)m, 0));
}

__device__ __forceinline__ void knn_body(const float* __restrict__ coords,
                                         int* __restrict__ nbhd,
                                         int b2, int tid, float* sc) {
    int batch = b2 >> 9;
    int qbase = (b2 & 511) << 2;
    const float* cb = coords + (size_t)batch * NN * 3;
    int wv = tid >> 6, lane = tid & 63;
    int ql = qbase + wv;
    float qx = cb[3 * ql], qy = cb[3 * ql + 1], qz = cb[3 * ql + 2];
#pragma unroll
    for (int h = 0; h < 2; ++h) {
        const float4* src = (const float4*)(cb + h * 3072);
        float4 a = src[3 * tid], b4 = src[3 * tid + 1], c4 = src[3 * tid + 2];
        int o = h * 1024 + tid * 4;
        float4 xs = {a.x, a.w, b4.z, c4.y};
        float4 ys = {a.y, b4.x, b4.w, c4.z};
        float4 zs = {a.z, b4.y, c4.x, c4.w};
        *(float4*)&sc[o]        = xs;
        *(float4*)&sc[2048 + o] = ys;
        *(float4*)&sc[4096 + o] = zs;
    }
    __syncthreads();

    // ---- pass 1: per-lane minimum only ----
    float mn = KNN_BIG;
#pragma unroll
    for (int g = 0; g < 8; ++g) {
        int base = g * 256 + lane * 4;
        float4 xs = *(const float4*)&sc[base];
        float4 ys = *(const float4*)&sc[2048 + base];
        float4 zs = *(const float4*)&sc[4096 + base];
        mn = fminf(mn, dist2f(xs.x - qx, ys.x - qy, zs.x - qz));
        mn = fminf(mn, dist2f(xs.y - qx, ys.y - qy, zs.y - qz));
        mn = fminf(mn, dist2f(xs.z - qx, ys.z - qy, zs.z - qz));
        mn = fminf(mn, dist2f(xs.w - qx, ys.w - qy, zs.w - qz));
    }

    // ---- U = 12th smallest of per-lane minima (>= exact T) ----
    float U = KNN_BIG;
    {
        float v = mn;
        int got = 0;
#pragma unroll 1
        for (int pass = 0; pass < 12; ++pass) {
            float mv = wave_min_bcast64(v);
            U = mv;
            got += (int)__popcll(__ballot(v == mv));
            if (got >= 12) break;
            if (v == mv) v = KNN_BIG;
        }
    }

    // ---- pass 2: recompute from LDS; atomic-slot compaction (unordered) ----
    float* lt_d2 = sc + 6144 + wv * KNN_CAP;
    int*   lt_ix = (int*)(sc + 6272) + wv * KNN_CAP;
    int*   eq_ix = (int*)(sc + 6400) + wv * 12;
    int*   cntp  = (int*)(sc + 6448) + wv * 2;
    if (lane == 0) { cntp[0] = 0; cntp[1] = 0; }
#pragma unroll 2
    for (int g = 0; g < 8; ++g) {
        int base = g * 256 + lane * 4;
        float4 xs = *(const float4*)&sc[base];
        float4 ys = *(const float4*)&sc[2048 + base];
        float4 zs = *(const float4*)&sc[4096 + base];
        float dd[4];
        dd[0] = dist2f(xs.x - qx, ys.x - qy, zs.x - qz);
        dd[1] = dist2f(xs.y - qx, ys.y - qy, zs.y - qz);
        dd[2] = dist2f(xs.z - qx, ys.z - qy, zs.z - qz);
        dd[3] = dist2f(xs.w - qx, ys.w - qy, zs.w - qz);
#pragma unroll
        for (int u = 0; u < 4; ++u) {
            float d2 = dd[u];
            if (d2 < U) {
                int s = atomicAdd(cntp, 1);
                if (s < KNN_CAP) { lt_d2[s] = d2; lt_ix[s] = base + u; }
            } else if (d2 == U) {
                int s = atomicAdd(cntp + 1, 1);
                if (s < 12) eq_ix[s] = base + u;
            }
        }
    }
    int cnt_lt = cntp[0], cnt_eq = cntp[1];

    float T = U;
    if (__builtin_expect(cnt_lt > KNN_CAP, 0)) {
        // exact fallback: per-lane top-12 from LDS -> exact T -> ballot recollect
        float kd12[12];
#pragma unroll
        for (int r = 0; r < 12; ++r) kd12[r] = KNN_BIG;
        for (int g = 0; g < 8; ++g) {
            int base = g * 256 + lane * 4;
            float4 xs = *(const float4*)&sc[base];
            float4 ys = *(const float4*)&sc[2048 + base];
            float4 zs = *(const float4*)&sc[4096 + base];
            float dd[4];
            dd[0] = dist2f(xs.x - qx, ys.x - qy, zs.x - qz);
            dd[1] = dist2f(xs.y - qx, ys.y - qy, zs.y - qz);
            dd[2] = dist2f(xs.z - qx, ys.z - qy, zs.z - qz);
            dd[3] = dist2f(xs.w - qx, ys.w - qy, zs.w - qz);
#pragma unroll
            for (int u = 0; u < 4; ++u) {
                float cv = dd[u];
#pragma unroll
                for (int r = 0; r < 12; ++r) {
                    float lo = fminf(kd12[r], cv);
                    cv = fmaxf(kd12[r], cv);
                    kd12[r] = lo;
                }
            }
        }
        int got = 0;
#pragma unroll 1
        for (int pass = 0; pass < 12; ++pass) {
            float mv = wave_min_bcast64(kd12[0]);
            T = mv;
            got += (int)__popcll(__ballot(kd12[0] == mv));
            if (got >= 12) break;
            if (kd12[0] == mv) {
#pragma unroll
                for (int r = 0; r < 11; ++r) kd12[r] = kd12[r + 1];
                kd12[11] = KNN_BIG;
            }
        }
        cnt_lt = 0; cnt_eq = 0;
        for (int g = 0; g < 8; ++g) {
            int base = g * 256 + lane * 4;
            float4 xs = *(const float4*)&sc[base];
            float4 ys = *(const float4*)&sc[2048 + base];
            float4 zs = *(const float4*)&sc[4096 + base];
            float dd[4];
            dd[0] = dist2f(xs.x - qx, ys.x - qy, zs.x - qz);
            dd[1] = dist2f(xs.y - qx, ys.y - qy, zs.y - qz);
            dd[2] = dist2f(xs.z - qx, ys.z - qy, zs.z - qz);
            dd[3] = dist2f(xs.w - qx, ys.w - qy, zs.w - qz);
#pragma unroll
            for (int u = 0; u < 4; ++u) {
                float d2 = dd[u];
                bool lt = d2 < T;
                unsigned long long bl = __ballot(lt);
                if (lt) {
                    int s = cnt_lt + lane_rank(bl);
                    if (s < KNN_CAP) { lt_d2[s] = d2; lt_ix[s] = base + u; }
                }
                cnt_lt += (int)__popcll(bl);
                bool eq = (d2 == T);
                unsigned long long be = __ballot(eq);
                if (eq) {
                    int s = cnt_eq + lane_rank(be);
                    if (s < 12) eq_ix[s] = base + u;
                }
                cnt_eq += (int)__popcll(be);
            }
        }
    }

    // ---- rank survivors by (d2, idx): exact reference stable top-k ----
    int C_lt = cnt_lt < KNN_CAP ? cnt_lt : KNN_CAP;
    int C_eq = cnt_eq < 12 ? cnt_eq : 12;
    int C = C_lt + C_eq;
    float md2 = KNN_BIG; int mix = 0x7FFFFFFF;
    if (lane < C_lt)      { md2 = lt_d2[lane]; mix = lt_ix[lane]; }
    else if (lane < C)    { md2 = T;           mix = eq_ix[lane - C_lt]; }
    int rank = 0;
#pragma unroll 1
    for (int j = 0; j < C; ++j) {
        float dj = __shfl(md2, j);
        int   ij = __shfl(mix, j);
        if (dj < md2 || (dj == md2 && ij < mix)) ++rank;
    }
    if (lane < C && rank < 12)
        nbhd[((size_t)batch * NN + ql) * KK + rank] = batch * NN + mix;
}

// ================= fused embed + knn(0) + prep (all weight tables) ===============
// blocks 0..2047: knn; 2048..6143: embed; 6144..9639: prep.
__global__ __launch_bounds__(256) void embed_knn_kernel(
    const float* __restrict__ feats, const float* __restrict__ w,
    const float* __restrict__ b, float* __restrict__ h,
    unsigned short* __restrict__ hbf,
    const float* __restrict__ coords, int* __restrict__ nbhd,
    const float* __restrict__ ew2, const float* __restrict__ cw1,
    const float* __restrict__ ew1, const float* __restrict__ nw1,
    const float* __restrict__ nw2,
    unsigned short* __restrict__ ew2frag, unsigned short* __restrict__ cw1frag,
    unsigned short* __restrict__ Btf, unsigned short* __restrict__ Bt1f,
    unsigned short* __restrict__ Bt2f)
{
    __shared__ __attribute__((aligned(16))) char smem[KNN_SMEM];
    int tid = threadIdx.x;
    int bid = (int)blockIdx.x;
    if (bid < 2048) {
        knn_body(coords, nbhd, bid, tid, (float*)smem);
    } else if (bid < 6144) {
        int idx = (bid - 2048) * 256 + tid;
        int n = idx >> 7, d = idx & 127;
        const float* fr = feats + n * 10;
        float acc = b[d];
#pragma unroll
        for (int f = 0; f < 10; ++f) acc = fmaf(fr[f], w[f * 128 + d], acc);
        h[idx] = acc;
        hbf[idx] = (unsigned short)f2bf(acc);
    } else {
        int t = (bid - 6144) * 256 + tid;
        if (t < 43008) {                              // 4 layers x (8704 + 2048)
            int l = t / 10752, r = t % 10752;
            if (r < 8704) {
                int kc = r >> 9, lane = (r >> 3) & 63, j = r & 7;
                int k = kc * 32 + ((lane >> 4) << 3) + j, n = lane & 15;
                float v = (k < 514) ? ew2[(size_t)l * 514 * 16 + k * 16 + n] : 0.0f;
                ew2frag[(size_t)l * 8704 + r] = (unsigned short)f2bf(v);
            } else {
                int r2 = r - 8704;
                int nb = r2 >> 9, lane = (r2 >> 3) & 63, j = r2 & 7;
                int c = ((lane >> 4) << 3) + j, n = nb * 16 + (lane & 15);
                float v = (c < 16) ? cw1[(size_t)l * 1024 + c * 64 + n] : 0.0f;
                cw1frag[(size_t)l * 2048 + r2] = (unsigned short)f2bf(v);
            }
        } else if (t < 600064) {
            // Btf[l][c][k]: c<514 -> ew1[l][k][c]; 514..1027 -> ew1[l][128+k][c-514]
            int t2 = t - 43008;
            int l = t2 / 139264, r2 = t2 % 139264;
            int k = r2 / 1088, c = r2 - k * 1088;
            const float* e1 = ew1 + (size_t)l * 257 * 514;
            float v = 0.0f;
            if (c < 514)       v = e1[k * 514 + c];
            else if (c < 1028) v = e1[(128 + k) * 514 + (c - 514)];
            Btf[(size_t)l * 139264 + c * 128 + k] = (unsigned short)f2bf(v);
        } else if (t < 763904) {
            // Bt1f[l][c(256)][k(160)] from nw1[l][144][256], k>=144 zero
            int t2 = t - 600064;
            int l = t2 / 40960, r2 = t2 % 40960;
            int c = r2 / 160, k = r2 - c * 160;
            float v = (k < 144) ? nw1[(size_t)l * 144 * 256 + k * 256 + c] : 0.0f;
            Bt1f[(size_t)l * 40960 + c * 160 + k] = (unsigned short)f2bf(v);
        } else if (t < 894976) {
            // Bt2f[l][c(128)][k(256)] from nw2[l][256][128]
            int t2 = t - 763904;
            int l = t2 / 32768, r2 = t2 % 32768;
            int c = r2 / 256, k = r2 - c * 256;
            float v = nw2[(size_t)l * 256 * 128 + k * 128 + c];
            Bt2f[(size_t)l * 32768 + c * 256 + k] = (unsigned short)f2bf(v);
        }
    }
}

// ================= fused node-MLP (mlp1+mlp2, t1 in LDS) + knn ====================
// Blocks 0..255: gemm (32 rows each); 256..256+knnb: knn. (R6-proven.)
__global__ __launch_bounds__(256, 4) void nodemlp_kernel(
    const unsigned short* __restrict__ hbf,   // [8192][128]
    const unsigned short* __restrict__ mbuf,  // [8192][16]
    const unsigned short* __restrict__ Bt1l,  // [256][160]
    const unsigned short* __restrict__ Bt2l,  // [128][256]
    const float* __restrict__ nb1l,           // 256
    const float* __restrict__ nb2l,           // 128
    const float* __restrict__ hin,            // resid [8192][128] fp32
    float* __restrict__ hout,
    unsigned short* __restrict__ hbfout,
    const float* __restrict__ coordsN, int* __restrict__ nbhd, int knnb)
{
    __shared__ __attribute__((aligned(16))) char smem[KNN_SMEM];
    int tid = threadIdx.x;
    int bid = (int)blockIdx.x;
    if (bid >= 256) {
        knn_body(coordsN, nbhd, bid - 256, tid, (float*)smem);
        return;
    }
    unsigned short (*sA)[40]   = (unsigned short(*)[40])smem;             // [32][40]
    unsigned short (*sB)[40]   = (unsigned short(*)[40])(smem + 2560);    // [128][40]
    unsigned short (*t1h)[136] = (unsigned short(*)[136])(smem + 12800);  // [32][136]
    int lane = tid & 63, w = tid >> 6, quad = lane >> 4, l16 = lane & 15;
    int rg = w >> 1, ch = w & 1;
    int rowBase = bid * 32;
    int bcol = tid >> 1, bs16 = (tid & 1) * 16;   // B staging: 128 cols x 2 uint4
    int ar = tid >> 2, ak8 = (tid & 3) * 8;       // A staging (tid<128): 32 rows

    f32x4 acc2[4];
#pragma unroll
    for (int ct = 0; ct < 4; ++ct) acc2[ct] = (f32x4){0.f, 0.f, 0.f, 0.f};

#pragma unroll 1
    for (int hf = 0; hf < 2; ++hf) {
        // ---- phase 1: t1[:, hf*128 .. +128] = silu(A(144) x Bt1 + nb1) ----
        f32x4 acc1[4];
#pragma unroll
        for (int ct = 0; ct < 4; ++ct) acc1[ct] = (f32x4){0.f, 0.f, 0.f, 0.f};
#pragma unroll 1
        for (int kc = 0; kc < 5; ++kc) {
            int k0 = kc * 32;
            if (tid < 128) {
                int kg = k0 + ak8;
                uint4 v = {0u, 0u, 0u, 0u};
                if (kg < 128)
                    v = *(const uint4*)&hbf[(size_t)(rowBase + ar) * 128 + kg];
                else if (kg < 144)
                    v = *(const uint4*)&mbuf[(size_t)(rowBase + ar) * 16 + (kg - 128)];
                *(uint4*)&sA[ar][ak8] = v;
            }
            {
                const unsigned short* bp = Bt1l + (size_t)(hf * 128 + bcol) * 160 + k0 + bs16;
                *(uint4*)&sB[bcol][bs16]     = *(const uint4*)bp;
                *(uint4*)&sB[bcol][bs16 + 8] = *(const uint4*)(bp + 8);
            }
            __syncthreads();
            bf16x8 a = *(const bf16x8*)&sA[rg * 16 + l16][quad * 8];
            bf16x8 bfr[4];
#pragma unroll
            for (int ct = 0; ct < 4; ++ct)
                bfr[ct] = *(const bf16x8*)&sB[ch * 64 + ct * 16 + l16][quad * 8];
#pragma unroll
            for (int ct = 0; ct < 4; ++ct)
                acc1[ct] = __builtin_amdgcn_mfma_f32_16x16x32_bf16(a, bfr[ct], acc1[ct], 0, 0, 0);
            __syncthreads();
        }
        // t1 epilogue -> LDS
#pragma unroll
        for (int ct = 0; ct < 4; ++ct) {
            int col = ch * 64 + ct * 16 + l16;
            float bv = nb1l[hf * 128 + col];
#pragma unroll
            for (int r = 0; r < 4; ++r)
                t1h[rg * 16 + quad * 4 + r][col] =
                    (unsigned short)f2bf(silu_f(acc1[ct][r] + bv));
        }
        __syncthreads();
        // ---- phase 2 partial: acc2 += t1h x Bt2[k = hf*128 ..] ----
#pragma unroll 1
        for (int kc2 = 0; kc2 < 4; ++kc2) {
            {
                const unsigned short* bp = Bt2l + (size_t)bcol * 256 + hf * 128 + kc2 * 32 + bs16;
                *(uint4*)&sB[bcol][bs16]     = *(const uint4*)bp;
                *(uint4*)&sB[bcol][bs16 + 8] = *(const uint4*)(bp + 8);
            }
            __syncthreads();
            bf16x8 a = *(const bf16x8*)&t1h[rg * 16 + l16][kc2 * 32 + quad * 8];
            bf16x8 bfr[4];
#pragma unroll
            for (int ct = 0; ct < 4; ++ct)
                bfr[ct] = *(const bf16x8*)&sB[ch * 64 + ct * 16 + l16][quad * 8];
#pragma unroll
            for (int ct = 0; ct < 4; ++ct)
                acc2[ct] = __builtin_amdgcn_mfma_f32_16x16x32_bf16(a, bfr[ct], acc2[ct], 0, 0, 0);
            __syncthreads();
        }
    }
    // ---- epilogue: h' = acc2 + nb2 + hin (residual); fp32 + bf16 out ----
#pragma unroll
    for (int ct = 0; ct < 4; ++ct) {
        int col = ch * 64 + ct * 16 + l16;
        float bv = nb2l[col];
#pragma unroll
        for (int r = 0; r < 4; ++r) {
            int row = rowBase + rg * 16 + quad * 4 + r;
            float v = acc2[ct][r] + bv + hin[(size_t)row * 128 + col];
            hout[(size_t)row * 128 + col] = v;
            hbfout[(size_t)row * 128 + col] = (unsigned short)f2bf(v);
        }
    }
}

// ================= merged P/Q GEMM: A (bf16 hbf) + B (bf16 Btf), uint4 staging ====
__global__ __launch_bounds__(256) void pq_gemm_kernel(
    const unsigned short* __restrict__ Abf,    // hbf [8192][128]
    const unsigned short* __restrict__ Bt,     // [1088 cols][128 k] bf16, layer slice
    unsigned short* __restrict__ PQb,
    const float* __restrict__ bias)
{
    __shared__ __attribute__((aligned(16))) unsigned short sA[128][40];
    __shared__ __attribute__((aligned(16))) unsigned short sBt[64][40];
    int tid = threadIdx.x;
    int lane = tid & 63, w = tid >> 6, quad = lane >> 4, l16 = lane & 15;
    int rowBase = blockIdx.y * 128;
    int colBase = blockIdx.x * 64;
    f32x4 acc[2][4];
#pragma unroll
    for (int rt = 0; rt < 2; ++rt)
#pragma unroll
        for (int ct = 0; ct < 4; ++ct) acc[rt][ct] = (f32x4){0.f, 0.f, 0.f, 0.f};

    int bc = tid >> 2, bk8 = (tid & 3) * 8;
    const unsigned short* bsrc = Bt + (size_t)(colBase + bc) * 128 + bk8;

#pragma unroll
    for (int kc = 0; kc < 4; ++kc) {
        int k0 = kc * 32;
#pragma unroll
        for (int p = 0; p < 2; ++p) {
            int e = tid + p * 256;
            int r = e >> 2, k8 = (e & 3) * 8;
            *(uint4*)&sA[r][k8] = *(const uint4*)&Abf[(size_t)(rowBase + r) * 128 + k0 + k8];
        }
        *(uint4*)&sBt[bc][bk8] = *(const uint4*)(bsrc + k0);
        __syncthreads();
        bf16x8 a[2], b[4];
#pragma unroll
        for (int rt = 0; rt < 2; ++rt)
            a[rt] = *(const bf16x8*)&sA[w * 32 + rt * 16 + l16][quad * 8];
#pragma unroll
        for (int ct = 0; ct < 4; ++ct)
            b[ct] = *(const bf16x8*)&sBt[ct * 16 + l16][quad * 8];
#pragma unroll
        for (int rt = 0; rt < 2; ++rt)
#pragma unroll
            for (int ct = 0; ct < 4; ++ct)
                acc[rt][ct] = __builtin_amdgcn_mfma_f32_16x16x32_bf16(a[rt], b[ct], acc[rt][ct], 0, 0, 0);
        __syncthreads();
    }
#pragma unroll
    for (int rt = 0; rt < 2; ++rt) {
#pragma unroll
        for (int ct = 0; ct < 4; ++ct) {
            int col = colBase + ct * 16 + l16;
            if (col < 1028) {
                bool isP = col < 514;
                int oc = isP ? col : col + 14;
                float bv = isP ? bias[col] : 0.0f;
#pragma unroll
                for (int r = 0; r < 4; ++r) {
                    int row = rowBase + w * 32 + rt * 16 + quad * 4 + r;
                    PQb[(size_t)row * 1056 + oc] = (unsigned short)f2bf(acc[rt][ct][r] + bv);
                }
            }
        }
    }
}

// ================= edge kernel: 192 thr / 4 nodes; P rows staged in LDS ==========
// P rows (node i side) are shared by 12 edges each: stage PQ[i][0..527] x 4 nodes
// (4224 B) once -> K-loop P reads become LDS broadcasts (same addr per quad group,
// free) and the pb[] global prefetch disappears (~17 MB/layer fewer L1/L2 reads,
// half the vmem slots in the hot loop).
__global__ __launch_bounds__(192, 6) void edge_kernel(
    const unsigned short* __restrict__ PQ, const int* __restrict__ nbhd,
    const float* __restrict__ cin, float* __restrict__ cout,
    unsigned short* __restrict__ mbuf,
    const float* __restrict__ wrow,            // raw ew1[l][256][0:514]
    const unsigned short* __restrict__ ew2f,   // [17][64][8] bf16 frags (global)
    const unsigned short* __restrict__ cw1f,   // [4][64][8] bf16 frags (global)
    const float* __restrict__ eb2l,            // 16
    const float* __restrict__ cb1l,            // 64
    const float* __restrict__ cw2l,            // 64
    const float* __restrict__ cb2l,            // 1
    const float* __restrict__ cscalel)         // 1
{
    __shared__ __attribute__((aligned(16))) float swl[544];
    __shared__ __attribute__((aligned(16))) unsigned short sP[4][528];
    __shared__ __attribute__((aligned(16))) unsigned short mbf[48][16];
    __shared__ __attribute__((aligned(16))) float mf32[48][16];
    __shared__ __attribute__((aligned(16))) float reld2[48][4];
    __shared__ float wall[48];
    int tid = threadIdx.x;

    // XCD swizzle: bid -> (batch, within-batch group); bijective over 2048.
    int bid = blockIdx.x;
    int rr8 = bid & 7, bsw = rr8 >> 1;
    int wsw = ((bid >> 3) << 1) | (rr8 & 1);
    int nodeBase = bsw * 2048 + wsw * 4;

    for (int idx = tid; idx < 544; idx += 192)
        swl[idx] = (idx < 514) ? wrow[idx] : 0.0f;
    // stage P rows: 4 nodes x 528 shorts = 264 uint4
    for (int u = tid; u < 264; u += 192) {
        int rr = u / 66, c8 = (u % 66) * 8;
        *(uint4*)&sP[rr][c8] = *(const uint4*)(PQ + (size_t)(nodeBase + rr) * 1056 + c8);
    }
    __syncthreads();

    int lane = tid & 63, w = tid >> 6;               // w in 0..2
    int quad = lane >> 4, e16 = lane & 15;
    int eloc = w * 16 + e16;                         // 0..47
    int nloc = eloc / 12;                            // 0..3
    int k12 = eloc - nloc * 12;
    int i = nodeBase + nloc;
    int j = nbhd[i * KK + k12];
    float cix = cin[i * 3], ciy = cin[i * 3 + 1], ciz = cin[i * 3 + 2];
    float rx = cix - cin[j * 3], ry = ciy - cin[j * 3 + 1], rz = ciz - cin[j * 3 + 2];
    float d2 = rx * rx + ry * ry + rz * rz;

    const unsigned short* Qp = PQ + (size_t)j * 1056 + 528 + quad * 8;

    uint4 qb[3];
    qb[0] = *(const uint4*)Qp;
    qb[1] = *(const uint4*)(Qp + 32);

    f32x4 acc = {0.0f, 0.0f, 0.0f, 0.0f};
#pragma unroll
    for (int kc = 0; kc < 16; ++kc) {
        int cur = kc % 3, nx = (kc + 2) % 3;
        if (kc < 14) {
            qb[nx] = *(const uint4*)(Qp + (kc + 2) * 32);
        }
        float p[8], q[8];
        upk8(*(const uint4*)&sP[nloc][quad * 8 + kc * 32], p);
        upk8(qb[cur], q);
        float4 w0 = *(const float4*)&swl[quad * 8 + kc * 32];
        float4 w1 = *(const float4*)&swl[quad * 8 + kc * 32 + 4];
        float h0 = silu_f(fmaf(d2, w0.x, p[0] + q[0]));
        float h1 = silu_f(fmaf(d2, w0.y, p[1] + q[1]));
        float h2 = silu_f(fmaf(d2, w0.z, p[2] + q[2]));
        float h3 = silu_f(fmaf(d2, w0.w, p[3] + q[3]));
        float h4 = silu_f(fmaf(d2, w1.x, p[4] + q[4]));
        float h5 = silu_f(fmaf(d2, w1.y, p[5] + q[5]));
        float h6 = silu_f(fmaf(d2, w1.z, p[6] + q[6]));
        float h7 = silu_f(fmaf(d2, w1.w, p[7] + q[7]));
        bf16x8 af;
        short2 r0 = pkbf(h0, h1), r1 = pkbf(h2, h3), r2 = pkbf(h4, h5), r3 = pkbf(h6, h7);
        af[0] = r0.x; af[1] = r0.y; af[2] = r1.x; af[3] = r1.y;
        af[4] = r2.x; af[5] = r2.y; af[6] = r3.x; af[7] = r3.y;
        bf16x8 bf = *(const bf16x8*)(ew2f + (((size_t)kc * 64 + lane) << 3));
        acc = __builtin_amdgcn_mfma_f32_16x16x32_bf16(af, bf, acc, 0, 0, 0);
    }
    {   // tail: k=512,513 (P from LDS, Q from global)
        unsigned up = *(const unsigned*)&sP[nloc][512];
        unsigned uq = *(const unsigned*)(PQ + (size_t)j * 1056 + 528 + 512);
        bf16x8 af = {0, 0, 0, 0, 0, 0, 0, 0};
        if (quad == 0) {
            float px = __uint_as_float(up << 16), py = __uint_as_float(up & 0xFFFF0000u);
            float qx = __uint_as_float(uq << 16), qy = __uint_as_float(uq & 0xFFFF0000u);
            af[0] = f2bf(silu_f(fmaf(d2, swl[512], px + qx)));
            af[1] = f2bf(silu_f(fmaf(d2, swl[513], py + qy)));
        }
        bf16x8 bf = *(const bf16x8*)(ew2f + (((size_t)16 * 64 + lane) << 3));
        acc = __builtin_amdgcn_mfma_f32_16x16x32_bf16(af, bf, acc, 0, 0, 0);
    }

    float eb = eb2l[e16];
    float m[4];
#pragma unroll
    for (int r = 0; r < 4; ++r) m[r] = silu_f(acc[r] + eb);

#pragma unroll
    for (int r = 0; r < 4; ++r) {
        int row = w * 16 + quad * 4 + r;
        mbf[row][e16] = (unsigned short)f2bf(m[r]);
        mf32[row][e16] = m[r];
    }
    if (quad == 0) {
        reld2[eloc][0] = rx; reld2[eloc][1] = ry;
        reld2[eloc][2] = rz; reld2[eloc][3] = d2;
    }
    __syncthreads();

    if (tid < 64) {
        int n = tid >> 4, ch = tid & 15;
        float s = 0.0f;
#pragma unroll
        for (int ke = 0; ke < KK; ++ke) s += mf32[n * 12 + ke][ch];
        mbuf[(size_t)(nodeBase + n) * 16 + ch] = (unsigned short)f2bf(s);
    }

    bf16x8 af2 = {0, 0, 0, 0, 0, 0, 0, 0};
    if (quad < 2) af2 = *(const bf16x8*)&mbf[w * 16 + e16][quad * 8];
    float wpart[4] = {0.0f, 0.0f, 0.0f, 0.0f};
#pragma unroll
    for (int nb = 0; nb < 4; ++nb) {
        bf16x8 cf = *(const bf16x8*)(cw1f + (((size_t)nb * 64 + lane) << 3));
        f32x4 z = {0.0f, 0.0f, 0.0f, 0.0f};
        f32x4 t = __builtin_amdgcn_mfma_f32_16x16x32_bf16(af2, cf, z, 0, 0, 0);
        int d = nb * 16 + e16;
        float cb = cb1l[d], cw = cw2l[d];
#pragma unroll
        for (int r = 0; r < 4; ++r)
            wpart[r] = fmaf(silu_f(t[r] + cb), cw, wpart[r]);
    }
#pragma unroll
    for (int o = 1; o < 16; o <<= 1)
#pragma unroll
        for (int r = 0; r < 4; ++r) wpart[r] += __shfl_xor(wpart[r], o);
    if (e16 == 0) {
        float cb2v = cb2l[0];
#pragma unroll
        for (int r = 0; r < 4; ++r) {
            float ww = wpart[r] + cb2v;
            ww = fminf(fmaxf(ww, -2.0f), 2.0f);
            wall[w * 16 + quad * 4 + r] = ww;
        }
    }
    __syncthreads();

    if (tid < 12) {
        int n = tid / 3, c = tid - n * 3;
        float cs = cscalel[0];
        float s = 0.0f;
#pragma unroll
        for (int ke = 0; ke < KK; ++ke) {
            int eo = n * 12 + ke;
            float d2e = reld2[eo][3];
            float f = wall[eo] * cs * __builtin_amdgcn_rcpf(fmaxf(sqrtf(d2e), 1e-8f));
            s = fmaf(f, reld2[eo][c], s);
        }
        int node = nodeBase + n;
        cout[node * 3 + c] = cin[node * 3 + c] + s;
    }
}

// ---------------- final: two-stage mean reduction ----------------
__global__ __launch_bounds__(256) void final1_kernel(const float* __restrict__ h,
                                                     float* __restrict__ part) {
    int b = blockIdx.x >> 5, sl = blockIdx.x & 31;
    int d = threadIdx.x & 127, half = threadIdx.x >> 7;
    const float* hp = h + ((size_t)b * NN + sl * 64) * DIMF;
    float acc = 0.0f;
    for (int n = half; n < 64; n += 2) acc += hp[(size_t)n * DIMF + d];
    __shared__ float red[256];
    red[threadIdx.x] = acc;
    __syncthreads();
    if (half == 0) part[(size_t)blockIdx.x * DIMF + d] = red[d] + red[d + 128];
}

__global__ __launch_bounds__(128) void final2_kernel(const float* __restrict__ part,
                                                     float* __restrict__ out) {
    int b = blockIdx.x, d = threadIdx.x;
    float acc = 0.0f;
#pragma unroll
    for (int s = 0; s < 32; ++s) acc += part[(size_t)(b * 32 + s) * DIMF + d];
    out[b * DIMF + d] = acc * (1.0f / NN);
}

extern "C" void kernel_launch(void* const* d_in, const int* in_sizes, int n_in,
                              void* d_out, int out_size, void* d_ws, size_t ws_size,
                              hipStream_t stream) {
    const float* feats  = (const float*)d_in[0];
    const float* coords = (const float*)d_in[1];
    // d_in[2] = mask (all true) -- unused
    const float* emb_w  = (const float*)d_in[3];
    const float* emb_b  = (const float*)d_in[4];
    const float* ew1    = (const float*)d_in[5];
    const float* eb1    = (const float*)d_in[6];
    const float* ew2    = (const float*)d_in[7];
    const float* eb2    = (const float*)d_in[8];
    const float* cw1    = (const float*)d_in[9];
    const float* cb1    = (const float*)d_in[10];
    const float* cw2    = (const float*)d_in[11];
    const float* cb2    = (const float*)d_in[12];
    const float* cscale = (const float*)d_in[13];
    const float* nw1    = (const float*)d_in[14];
    const float* nb1    = (const float*)d_in[15];
    const float* nw2    = (const float*)d_in[16];
    const float* nb2    = (const float*)d_in[17];

    // workspace: within proven 47,513,600 B footprint
    char* ws = (char*)d_ws;
    float* h0     = (float*)(ws + 0);
    float* h1     = (float*)(ws + 4194304);
    float* c0     = (float*)(ws + 8388608);
    float* c1     = (float*)(ws + 8486912);
    int*   nbhd   = (int*)  (ws + 8585216);
    unsigned short* hbf0 = (unsigned short*)(ws + 8978432);     // 2,097,152 B
    unsigned short* hbf1 = (unsigned short*)(ws + 11075584);    // -> 13,172,736
    unsigned short* PQb = (unsigned short*)(ws + 13697024);     // 8192x1056 bf16
    unsigned short* ew2frag = (unsigned short*)(ws + 35651584); // 69,632 B
    unsigned short* cw1frag = (unsigned short*)(ws + 35721216); // 16,384 B
    unsigned short* Btf     = (unsigned short*)(ws + 35737600); // 1,114,112 -> 36,851,712
    unsigned short* mbuf    = (unsigned short*)(ws + 36851712); // 262,144 -> 37,113,856
    unsigned short* Bt1f    = (unsigned short*)(ws + 37113856); // 327,680 -> 37,441,536
    unsigned short* Bt2f    = (unsigned short*)(ws + 37441536); // 262,144 -> 37,703,680
    float* part   = (float*)(ws + 13697024);                    // alias, after layers

    float* hbuf[2] = {h0, h1};
    float* cbuf[2] = {c0, c1};
    unsigned short* hbfb[2] = {hbf0, hbf1};

    // fused embed + knn(0) + prep: 0..2047 knn, 2048..6143 embed, 6144..9639 prep
    embed_knn_kernel<<<9640, 256, 0, stream>>>(feats, emb_w, emb_b, h0, hbf0,
        coords, nbhd, ew2, cw1, ew1, nw1, nw2, ew2frag, cw1frag, Btf, Bt1f, Bt2f);

    for (int l = 0; l < 4; ++l) {
        const float* hin  = hbuf[l & 1];
        float*       hout = hbuf[(l + 1) & 1];
        unsigned short* hbfin  = hbfb[l & 1];
        unsigned short* hbfout = hbfb[(l + 1) & 1];
        const float* cin  = (l == 0) ? coords : cbuf[(l - 1) & 1];
        float*       cout = cbuf[l & 1];
        const float* ew1l = ew1 + (size_t)l * 257 * 514;

        pq_gemm_kernel<<<dim3(17, 64), 256, 0, stream>>>(
            hbfin, Btf + (size_t)l * 139264, PQb, eb1 + l * 514);

        edge_kernel<<<NODES / 4, 192, 0, stream>>>(PQb, nbhd, cin, cout, mbuf,
            ew1l + 256 * 514, ew2frag + (size_t)l * 8704, cw1frag + (size_t)l * 2048,
            eb2 + l * 16, cb1 + l * 64, cw2 + l * 64, cb2 + l, cscale + l);

        // fused node-MLP (256 gemm blocks first) + full knn(l+1) (2048 blocks)
        int knnb = (l < 3) ? 2048 : 0;
        nodemlp_kernel<<<256 + knnb, 256, 0, stream>>>(
            hbfin, mbuf, Bt1f + (size_t)l * 40960, Bt2f + (size_t)l * 32768,
            nb1 + l * 256, nb2 + l * 128, hin, hout, hbfout,
            cout, nbhd, knnb);
    }

    final1_kernel<<<NB * 32, 256, 0, stream>>>(hbuf[0], part);
    final2_kernel<<<NB, 128, 0, stream>>>(part, (float*)d_out);
}